// Round 1
// baseline (8009.492 us; speedup 1.0000x reference)
//
#include <hip/hip_runtime.h>
#include <math.h>

#define N_NODES 50000
#define N_EDGES 800000
#define M_HID   128
#define P_FEAT  256
#define C_OUT   40
#define PWR_ITERS 50
#define FP_ITERS  30
#define KAPPA 0.9f

// ---------------- power iteration ----------------

__global__ void fill_v_kernel(float* v, float* av, int n, float val) {
    int i = blockIdx.x * blockDim.x + threadIdx.x;
    if (i < n) { v[i] = val; av[i] = 0.f; }
}

__global__ void scatter_av(const int* __restrict__ src, const int* __restrict__ dst,
                           const float* __restrict__ w, const float* __restrict__ v,
                           float* av, int E) {
    int e = blockIdx.x * blockDim.x + threadIdx.x;
    if (e < E) atomicAdd(&av[src[e]], w[e] * v[dst[e]]);
}

__global__ void reduce_ss(const float* __restrict__ av, int n, float* out) {
    float s = 0.f;
    for (int i = blockIdx.x * blockDim.x + threadIdx.x; i < n; i += gridDim.x * blockDim.x) {
        float x = av[i]; s += x * x;
    }
    for (int o = 32; o > 0; o >>= 1) s += __shfl_down(s, o, 64);
    __shared__ float ls[16];
    int lane = threadIdx.x & 63, wid = threadIdx.x >> 6;
    if (lane == 0) ls[wid] = s;
    __syncthreads();
    if (threadIdx.x == 0) {
        float t = 0.f; int nw = blockDim.x >> 6;
        for (int i = 0; i < nw; ++i) t += ls[i];
        atomicAdd(out, t);
    }
}

__global__ void scale_v(const float* __restrict__ ssp, float* v, float* av, int n) {
    int i = blockIdx.x * blockDim.x + threadIdx.x;
    if (i < n) {
        float norm = sqrtf(*ssp) + 1e-12f;
        v[i] = av[i] / norm;
        av[i] = 0.f;   // reset for next scatter
    }
}

// ---------------- L1-ball row projection of W ----------------
// one block, 128 threads; thread t owns row t. buf[i][t] layout -> bank = t%32.

__global__ __launch_bounds__(128) void project_w(const float* __restrict__ W,
                                                 const float* __restrict__ rho2,
                                                 float* Wp, float* WpT) {
    __shared__ float buf[128][128];
    int t = threadIdx.x;
    float radius = KAPPA / sqrtf(*rho2);
    float asum = 0.f;
    for (int i = 0; i < 128; ++i) {
        float x = fabsf(W[t * 128 + i]);
        buf[i][t] = x; asum += x;
    }
    bool needs = asum > radius;
    float theta = 0.f;
    if (needs) {
        // insertion sort descending in LDS column
        for (int i = 1; i < 128; ++i) {
            float key = buf[i][t];
            int j = i - 1;
            while (j >= 0 && buf[j][t] < key) { buf[j + 1][t] = buf[j][t]; --j; }
            buf[j + 1][t] = key;
        }
        // count positions where s_k * k > cs_k - radius (mirrors jnp sum of bools)
        float cs = 0.f; int cnt = 0;
        for (int i = 0; i < 128; ++i) {
            cs += buf[i][t];
            if (buf[i][t] * (float)(i + 1) > cs - radius) cnt = cnt + 1;
        }
        float cs_r = 0.f;
        for (int i = 0; i < cnt; ++i) cs_r += buf[i][t];
        theta = (cs_r - radius) / (float)cnt;
    }
    for (int i = 0; i < 128; ++i) {
        float w0 = W[t * 128 + i];
        float o;
        if (needs) {
            float a = fabsf(w0) - theta;
            o = (a > 0.f) ? ((w0 > 0.f) ? a : -a) : 0.f;
        } else o = w0;
        Wp[t * 128 + i] = o;
        WpT[i * 128 + t] = o;
    }
}

// ---------------- CSR build (by dst) ----------------

__global__ void count_deg(const int* __restrict__ dst, int* deg, int E) {
    int e = blockIdx.x * blockDim.x + threadIdx.x;
    if (e < E) atomicAdd(&deg[dst[e]], 1);
}

__global__ __launch_bounds__(1024) void scan_offsets(const int* __restrict__ deg,
                                                     int* offsets, int* cursor, int n) {
    __shared__ int partial[1024];
    int tid = threadIdx.x;
    int chunk = (n + 1023) / 1024;
    int lo = tid * chunk;
    int hi = lo + chunk; if (hi > n) hi = n; if (lo > n) lo = n;
    int s = 0;
    for (int i = lo; i < hi; ++i) s += deg[i];
    partial[tid] = s;
    __syncthreads();
    for (int od = 1; od < 1024; od <<= 1) {
        int val = 0;
        if (tid >= od) val = partial[tid - od];
        __syncthreads();
        if (tid >= od) partial[tid] += val;
        __syncthreads();
    }
    int base = (tid == 0) ? 0 : partial[tid - 1];
    for (int i = lo; i < hi; ++i) {
        offsets[i] = base; cursor[i] = base;
        base += deg[i];
    }
    if (tid == 1023) offsets[n] = partial[1023];
}

__global__ void fill_csr(const int* __restrict__ src, const int* __restrict__ dst,
                         const float* __restrict__ w, int* cursor,
                         int* csr_src, float* csr_w, int E) {
    int e = blockIdx.x * blockDim.x + threadIdx.x;
    if (e < E) {
        int p = atomicAdd(&cursor[dst[e]], 1);
        csr_src[p] = src[e];
        csr_w[p] = w[e];
    }
}

// ---------------- small transposes ----------------

__global__ void transpose_om(const float* __restrict__ Om, float* OmT) {
    int idx = blockIdx.x * blockDim.x + threadIdx.x;  // 128*256
    if (idx < 128 * 256) {
        int t = idx / 256, k = idx % 256;
        OmT[k * 128 + t] = Om[idx];
    }
}

__global__ void transpose_x0(const float* __restrict__ X0, float* Xt, int n) {
    __shared__ float tile[32][33];
    int jb = blockIdx.x * 32, tb = blockIdx.y * 32;
    int tx = threadIdx.x, ty = threadIdx.y;   // 32 x 8
    for (int r = 0; r < 32; r += 8) {
        int t = tb + ty + r, j = jb + tx;
        tile[ty + r][tx] = (j < n) ? X0[(size_t)t * n + j] : 0.f;
    }
    __syncthreads();
    for (int r = 0; r < 32; r += 8) {
        int j = jb + ty + r, t = tb + tx;
        if (j < n) Xt[(size_t)j * 128 + t] = tile[tx][ty + r];
    }
}

// ---------------- dense GEMMs ----------------
// Ut[j,t] = sum_k F[k*n+j] * OmT[k*128+t]   (M=n, N=128, K=256)
__global__ __launch_bounds__(256) void gemm_u(const float* __restrict__ F,
                                              const float* __restrict__ OmT,
                                              float* __restrict__ C, int n) {
    __shared__ float Fs[16][129];
    __shared__ float Bs[16][129];
    int j0 = blockIdx.x * 128;
    int tid = threadIdx.x;
    int tj = tid >> 4, tg = tid & 15;
    float acc[8][8] = {};
    for (int k0 = 0; k0 < 256; k0 += 16) {
        for (int r = 0; r < 8; ++r) {
            int idx = r * 256 + tid;
            int kk = idx >> 7, jj = idx & 127;
            int j = j0 + jj;
            Fs[kk][jj] = (j < n) ? F[(size_t)(k0 + kk) * n + j] : 0.f;
            Bs[kk][jj] = OmT[(k0 + kk) * 128 + jj];
        }
        __syncthreads();
        for (int kk = 0; kk < 16; ++kk) {
            float a[8], b[8];
            #pragma unroll
            for (int u = 0; u < 8; ++u) a[u] = Fs[kk][tj + 16 * u];
            #pragma unroll
            for (int u = 0; u < 8; ++u) b[u] = Bs[kk][tg + 16 * u];
            #pragma unroll
            for (int x = 0; x < 8; ++x)
                #pragma unroll
                for (int y = 0; y < 8; ++y)
                    acc[x][y] += a[x] * b[y];
        }
        __syncthreads();
    }
    for (int x = 0; x < 8; ++x) {
        int j = j0 + tj + 16 * x;
        if (j < n)
            for (int y = 0; y < 8; ++y)
                C[(size_t)j * 128 + tg + 16 * y] = acc[x][y];
    }
}

// Xt[j,t] = relu( sum_k Yt[j,k] * WpT[k*128+t] + bt[j,t] )   (K=128)
__global__ __launch_bounds__(256) void gemm_relu(const float* __restrict__ Yt,
                                                 const float* __restrict__ WpT,
                                                 const float* __restrict__ bt,
                                                 float* __restrict__ Xt, int n) {
    __shared__ float As[16][129];
    __shared__ float Bs[16][129];
    int j0 = blockIdx.x * 128;
    int tid = threadIdx.x;
    int tj = tid >> 4, tg = tid & 15;
    float acc[8][8] = {};
    for (int k0 = 0; k0 < 128; k0 += 16) {
        for (int r = 0; r < 8; ++r) {
            int idx = r * 256 + tid;
            { // A tile: consecutive tid -> consecutive k (64B runs)
                int jj = idx >> 4, kk = idx & 15;
                int j = j0 + jj;
                As[kk][jj] = (j < n) ? Yt[(size_t)j * 128 + k0 + kk] : 0.f;
            }
            { // B tile
                int kk = idx >> 7, tt = idx & 127;
                Bs[kk][tt] = WpT[(k0 + kk) * 128 + tt];
            }
        }
        __syncthreads();
        for (int kk = 0; kk < 16; ++kk) {
            float a[8], b[8];
            #pragma unroll
            for (int u = 0; u < 8; ++u) a[u] = As[kk][tj + 16 * u];
            #pragma unroll
            for (int u = 0; u < 8; ++u) b[u] = Bs[kk][tg + 16 * u];
            #pragma unroll
            for (int x = 0; x < 8; ++x)
                #pragma unroll
                for (int y = 0; y < 8; ++y)
                    acc[x][y] += a[x] * b[y];
        }
        __syncthreads();
    }
    for (int x = 0; x < 8; ++x) {
        int j = j0 + tj + 16 * x;
        if (j < n)
            for (int y = 0; y < 8; ++y) {
                int c = tg + 16 * y;
                float v = acc[x][y] + bt[(size_t)j * 128 + c];
                Xt[(size_t)j * 128 + c] = (v > 0.f) ? v : 0.f;
            }
    }
}

// ---------------- sparse X*A (gather over CSR-by-dst) ----------------

__global__ __launch_bounds__(128) void spmm_csr(const int* __restrict__ offsets,
                                                const int* __restrict__ csr_src,
                                                const float* __restrict__ csr_w,
                                                const float* __restrict__ Xin,
                                                float* __restrict__ Yout) {
    int j = blockIdx.x;
    int t = threadIdx.x;
    int lo = offsets[j], hi = offsets[j + 1];
    float acc = 0.f;
    for (int e = lo; e < hi; ++e) {
        acc += csr_w[e] * Xin[(size_t)csr_src[e] * 128 + t];
    }
    Yout[(size_t)j * 128 + t] = acc;
}

// ---------------- final: normalize rows + H @ Vw^T ----------------

__global__ __launch_bounds__(128) void final_out(const float* __restrict__ Xt,
                                                 const float* __restrict__ Vw,
                                                 float* __restrict__ out) {
    __shared__ float h[128];
    __shared__ float red[2];
    int j = blockIdx.x, t = threadIdx.x;
    float x = Xt[(size_t)j * 128 + t];
    float s = x * x;
    for (int o = 32; o > 0; o >>= 1) s += __shfl_down(s, o, 64);
    if ((t & 63) == 0) red[t >> 6] = s;
    __syncthreads();
    float norm = sqrtf(red[0] + red[1]);
    float inv = 1.f / fmaxf(norm, 1e-12f);
    h[t] = x * inv;
    __syncthreads();
    if (t < C_OUT) {
        float acc = 0.f;
        for (int k = 0; k < 128; ++k) acc += h[k] * Vw[t * 128 + k];
        out[(size_t)j * C_OUT + t] = acc;
    }
}

// ---------------- launch ----------------

extern "C" void kernel_launch(void* const* d_in, const int* in_sizes, int n_in,
                              void* d_out, int out_size, void* d_ws, size_t ws_size,
                              hipStream_t stream) {
    const float* F    = (const float*)d_in[0];   // (256, 50000)
    const float* W    = (const float*)d_in[1];   // (128, 128)
    const float* Om   = (const float*)d_in[2];   // (128, 256)
    const float* Vw   = (const float*)d_in[3];   // (40, 128)
    const float* X0   = (const float*)d_in[4];   // (128, 50000)
    const float* ew   = (const float*)d_in[5];   // (E,)
    const int*   esrc = (const int*)d_in[6];
    const int*   edst = (const int*)d_in[7];
    float* out = (float*)d_out;
    (void)in_sizes; (void)n_in; (void)out_size; (void)ws_size;

    char* ws = (char*)d_ws;
    size_t off = 0;
    auto alloc = [&](size_t bytes) -> void* {
        void* p = ws + off;
        off = (off + bytes + 255) & ~(size_t)255;
        return p;
    };
    float* v       = (float*)alloc((size_t)N_NODES * 4);
    float* av      = (float*)alloc((size_t)N_NODES * 4);
    float* ss      = (float*)alloc(64 * 4);
    int*   deg     = (int*)  alloc((size_t)(N_NODES + 1) * 4);
    int*   offs    = (int*)  alloc((size_t)(N_NODES + 1) * 4);
    int*   cursor  = (int*)  alloc((size_t)N_NODES * 4);
    int*   csr_src = (int*)  alloc((size_t)N_EDGES * 4);
    float* csr_w   = (float*)alloc((size_t)N_EDGES * 4);
    float* Wp      = (float*)alloc(128 * 128 * 4);
    float* WpT     = (float*)alloc(128 * 128 * 4);
    float* OmT     = (float*)alloc(256 * 128 * 4);
    float* bt      = (float*)alloc((size_t)N_NODES * 128 * 4);
    float* Yt      = (float*)alloc((size_t)N_NODES * 128 * 4);
    float* Xt      = (float*)alloc((size_t)N_NODES * 128 * 4);

    hipMemsetAsync(ss, 0, 64 * 4, stream);
    hipMemsetAsync(deg, 0, (size_t)(N_NODES + 1) * 4, stream);

    // ---- power iteration for spectral radius ----
    fill_v_kernel<<<(N_NODES + 255) / 256, 256, 0, stream>>>(
        v, av, N_NODES, 1.f / sqrtf((float)N_NODES));
    for (int it = 0; it < PWR_ITERS; ++it) {
        scatter_av<<<(N_EDGES + 255) / 256, 256, 0, stream>>>(esrc, edst, ew, v, av, N_EDGES);
        reduce_ss<<<256, 256, 0, stream>>>(av, N_NODES, ss + it);
        scale_v<<<(N_NODES + 255) / 256, 256, 0, stream>>>(ss + it, v, av, N_NODES);
    }
    scatter_av<<<(N_EDGES + 255) / 256, 256, 0, stream>>>(esrc, edst, ew, v, av, N_EDGES);
    reduce_ss<<<256, 256, 0, stream>>>(av, N_NODES, ss + PWR_ITERS);

    // ---- project W rows onto L1 ball of radius kappa/rho ----
    project_w<<<1, 128, 0, stream>>>(W, ss + PWR_ITERS, Wp, WpT);

    // ---- CSR by dst ----
    count_deg<<<(N_EDGES + 255) / 256, 256, 0, stream>>>(edst, deg, N_EDGES);
    scan_offsets<<<1, 1024, 0, stream>>>(deg, offs, cursor, N_NODES);
    fill_csr<<<(N_EDGES + 255) / 256, 256, 0, stream>>>(esrc, edst, ew, cursor,
                                                        csr_src, csr_w, N_EDGES);

    // ---- b = (Omega_1 @ U) @ A ----
    transpose_om<<<(128 * 256 + 255) / 256, 256, 0, stream>>>(Om, OmT);
    gemm_u<<<(N_NODES + 127) / 128, 256, 0, stream>>>(F, OmT, Yt, N_NODES);   // Ut in Yt
    spmm_csr<<<N_NODES, 128, 0, stream>>>(offs, csr_src, csr_w, Yt, bt);

    // ---- fixed point ----
    transpose_x0<<<dim3((N_NODES + 31) / 32, 4), dim3(32, 8), 0, stream>>>(X0, Xt, N_NODES);
    for (int it = 0; it < FP_ITERS; ++it) {
        spmm_csr<<<N_NODES, 128, 0, stream>>>(offs, csr_src, csr_w, Xt, Yt);
        gemm_relu<<<(N_NODES + 127) / 128, 256, 0, stream>>>(Yt, WpT, bt, Xt, N_NODES);
    }

    // ---- output ----
    final_out<<<N_NODES, 128, 0, stream>>>(Xt, Vw, out);
}

// Round 2
// 7086.595 us; speedup vs baseline: 1.1302x; 1.1302x over previous
//
#include <hip/hip_runtime.h>
#include <math.h>

#define N_NODES 50000
#define N_EDGES 800000
#define M_HID   128
#define P_FEAT  256
#define C_OUT   40
#define PWR_ITERS 50
#define FP_ITERS  30
#define KAPPA 0.9f

// ---------------- power iteration ----------------
// Double-buffered: scatter reads unnormalized prev Av and folds 1/(norm+eps);
// reduce_zero computes ||.||^2 of the new vector AND zeroes the other buffer.

__global__ void fill_pow(float* buf0, float* buf1, float* ss, int n, float val) {
    int i = blockIdx.x * blockDim.x + threadIdx.x;
    if (i < n) { buf0[i] = val; buf1[i] = 0.f; }
    if (blockIdx.x == 0 && threadIdx.x < 64) ss[threadIdx.x] = (threadIdx.x == 0) ? 1.f : 0.f;
}

__global__ void scatter_pow(const int* __restrict__ src, const int* __restrict__ dst,
                            const float* __restrict__ w, const float* __restrict__ vin,
                            const float* __restrict__ norm2, float* vout, int E) {
    int e = blockIdx.x * blockDim.x + threadIdx.x;
    if (e >= E) return;
    float inv = 1.f / (sqrtf(*norm2) + 1e-12f);
    atomicAdd(&vout[src[e]], w[e] * vin[dst[e]] * inv);
}

__global__ void reduce_zero(const float* __restrict__ av, float* zbuf, int n, float* out) {
    float s = 0.f;
    for (int i = blockIdx.x * blockDim.x + threadIdx.x; i < n; i += gridDim.x * blockDim.x) {
        float x = av[i]; s += x * x;
        zbuf[i] = 0.f;
    }
    for (int o = 32; o > 0; o >>= 1) s += __shfl_down(s, o, 64);
    __shared__ float ls[16];
    int lane = threadIdx.x & 63, wid = threadIdx.x >> 6;
    if (lane == 0) ls[wid] = s;
    __syncthreads();
    if (threadIdx.x == 0) {
        float t = 0.f; int nw = blockDim.x >> 6;
        for (int i = 0; i < nw; ++i) t += ls[i];
        atomicAdd(out, t);
    }
}

// ---------------- L1-ball row projection of W ----------------
// one block per row, 128 threads; rank-based parallel sort + LDS scan.

__global__ __launch_bounds__(128) void project_w(const float* __restrict__ W,
                                                 const float* __restrict__ rho2,
                                                 float* Wp, float* WpT) {
    __shared__ float sa[128];
    __shared__ float ssort[128];
    __shared__ float sc[128];
    __shared__ int cnt2[2];
    int r = blockIdx.x, t = threadIdx.x;
    float radius = KAPPA / sqrtf(*rho2);
    float w0 = W[r * 128 + t];
    float a = fabsf(w0);
    sa[t] = a;
    __syncthreads();
    // stable descending rank
    int rank = 0;
    #pragma unroll 8
    for (int j = 0; j < 128; ++j) {
        float aj = sa[j];
        rank += (aj > a) || (aj == a && j < t);
    }
    ssort[rank] = a;
    __syncthreads();
    sc[t] = ssort[t];
    __syncthreads();
    // inclusive Hillis-Steele scan
    for (int off = 1; off < 128; off <<= 1) {
        float add = (t >= off) ? sc[t - off] : 0.f;
        __syncthreads();
        sc[t] += add;
        __syncthreads();
    }
    bool flag = ssort[t] * (float)(t + 1) > sc[t] - radius;
    unsigned long long b = __ballot(flag);
    if ((t & 63) == 0) cnt2[t >> 6] = __popcll(b);
    __syncthreads();
    int rho = cnt2[0] + cnt2[1];
    float total = sc[127];
    bool needs = total > radius;
    float theta = (sc[rho - 1] - radius) / (float)rho;
    float o;
    if (needs) {
        float am = a - theta;
        o = (am > 0.f) ? ((w0 > 0.f) ? am : -am) : 0.f;
    } else o = w0;
    Wp[r * 128 + t] = o;
    WpT[t * 128 + r] = o;
}

// ---------------- CSR build (by dst) ----------------

__global__ void count_deg(const int* __restrict__ dst, int* deg, int E) {
    int e = blockIdx.x * blockDim.x + threadIdx.x;
    if (e < E) atomicAdd(&deg[dst[e]], 1);
}

__global__ __launch_bounds__(1024) void scan_offsets(const int* __restrict__ deg,
                                                     int* offsets, int* cursor, int n) {
    __shared__ int partial[1024];
    int tid = threadIdx.x;
    int chunk = (n + 1023) / 1024;
    int lo = tid * chunk;
    int hi = lo + chunk; if (hi > n) hi = n; if (lo > n) lo = n;
    int s = 0;
    for (int i = lo; i < hi; ++i) s += deg[i];
    partial[tid] = s;
    __syncthreads();
    for (int od = 1; od < 1024; od <<= 1) {
        int val = 0;
        if (tid >= od) val = partial[tid - od];
        __syncthreads();
        if (tid >= od) partial[tid] += val;
        __syncthreads();
    }
    int base = (tid == 0) ? 0 : partial[tid - 1];
    for (int i = lo; i < hi; ++i) {
        offsets[i] = base; cursor[i] = base;
        base += deg[i];
    }
    if (tid == 1023) offsets[n] = partial[1023];
}

__global__ void fill_csr(const int* __restrict__ src, const int* __restrict__ dst,
                         const float* __restrict__ w, int* cursor,
                         int* csr_src, float* csr_w, int E) {
    int e = blockIdx.x * blockDim.x + threadIdx.x;
    if (e < E) {
        int p = atomicAdd(&cursor[dst[e]], 1);
        csr_src[p] = src[e];
        csr_w[p] = w[e];
    }
}

// ---------------- small transposes ----------------

__global__ void transpose_om(const float* __restrict__ Om, float* OmT) {
    int idx = blockIdx.x * blockDim.x + threadIdx.x;  // 128*256
    if (idx < 128 * 256) {
        int t = idx / 256, k = idx % 256;
        OmT[k * 128 + t] = Om[idx];
    }
}

__global__ void transpose_x0(const float* __restrict__ X0, float* Xt, int n) {
    __shared__ float tile[32][33];
    int jb = blockIdx.x * 32, tb = blockIdx.y * 32;
    int tx = threadIdx.x, ty = threadIdx.y;   // 32 x 8
    for (int r = 0; r < 32; r += 8) {
        int t = tb + ty + r, j = jb + tx;
        tile[ty + r][tx] = (j < n) ? X0[(size_t)t * n + j] : 0.f;
    }
    __syncthreads();
    for (int r = 0; r < 32; r += 8) {
        int j = jb + ty + r, t = tb + tx;
        if (j < n) Xt[(size_t)j * 128 + t] = tile[tx][ty + r];
    }
}

// ---------------- dense GEMMs ----------------
// Ut[j,t] = sum_k F[k*n+j] * OmT[k*128+t]   (M=n, N=128, K=256)
__global__ __launch_bounds__(256) void gemm_u(const float* __restrict__ F,
                                              const float* __restrict__ OmT,
                                              float* __restrict__ C, int n) {
    __shared__ float Fs[16][129];
    __shared__ float Bs[16][129];
    int j0 = blockIdx.x * 128;
    int tid = threadIdx.x;
    int tj = tid >> 4, tg = tid & 15;
    float acc[8][8] = {};
    for (int k0 = 0; k0 < 256; k0 += 16) {
        for (int r = 0; r < 8; ++r) {
            int idx = r * 256 + tid;
            int kk = idx >> 7, jj = idx & 127;
            int j = j0 + jj;
            Fs[kk][jj] = (j < n) ? F[(size_t)(k0 + kk) * n + j] : 0.f;
            Bs[kk][jj] = OmT[(k0 + kk) * 128 + jj];
        }
        __syncthreads();
        for (int kk = 0; kk < 16; ++kk) {
            float a[8], b[8];
            #pragma unroll
            for (int u = 0; u < 8; ++u) a[u] = Fs[kk][tj + 16 * u];
            #pragma unroll
            for (int u = 0; u < 8; ++u) b[u] = Bs[kk][tg + 16 * u];
            #pragma unroll
            for (int x = 0; x < 8; ++x)
                #pragma unroll
                for (int y = 0; y < 8; ++y)
                    acc[x][y] += a[x] * b[y];
        }
        __syncthreads();
    }
    for (int x = 0; x < 8; ++x) {
        int j = j0 + tj + 16 * x;
        if (j < n)
            for (int y = 0; y < 8; ++y)
                C[(size_t)j * 128 + tg + 16 * y] = acc[x][y];
    }
}

// Xt[j,t] = relu( sum_k Yt[j,k] * WpT[k*128+t] + bt[j,t] )   (K=128)
__global__ __launch_bounds__(256) void gemm_relu(const float* __restrict__ Yt,
                                                 const float* __restrict__ WpT,
                                                 const float* __restrict__ bt,
                                                 float* __restrict__ Xt, int n) {
    __shared__ float As[16][129];
    __shared__ float Bs[16][129];
    int j0 = blockIdx.x * 128;
    int tid = threadIdx.x;
    int tj = tid >> 4, tg = tid & 15;
    float acc[8][8] = {};
    for (int k0 = 0; k0 < 128; k0 += 16) {
        for (int r = 0; r < 8; ++r) {
            int idx = r * 256 + tid;
            { // A tile
                int jj = idx >> 4, kk = idx & 15;
                int j = j0 + jj;
                As[kk][jj] = (j < n) ? Yt[(size_t)j * 128 + k0 + kk] : 0.f;
            }
            { // B tile
                int kk = idx >> 7, tt = idx & 127;
                Bs[kk][tt] = WpT[(k0 + kk) * 128 + tt];
            }
        }
        __syncthreads();
        for (int kk = 0; kk < 16; ++kk) {
            float a[8], b[8];
            #pragma unroll
            for (int u = 0; u < 8; ++u) a[u] = As[kk][tj + 16 * u];
            #pragma unroll
            for (int u = 0; u < 8; ++u) b[u] = Bs[kk][tg + 16 * u];
            #pragma unroll
            for (int x = 0; x < 8; ++x)
                #pragma unroll
                for (int y = 0; y < 8; ++y)
                    acc[x][y] += a[x] * b[y];
        }
        __syncthreads();
    }
    for (int x = 0; x < 8; ++x) {
        int j = j0 + tj + 16 * x;
        if (j < n)
            for (int y = 0; y < 8; ++y) {
                int c = tg + 16 * y;
                float v = acc[x][y] + bt[(size_t)j * 128 + c];
                Xt[(size_t)j * 128 + c] = (v > 0.f) ? v : 0.f;
            }
    }
}

// ---------------- sparse X*A: wave-per-node gather over CSR-by-dst ----------------

__global__ __launch_bounds__(256) void spmm_csr(const int* __restrict__ offsets,
                                                const int* __restrict__ csr_src,
                                                const float* __restrict__ csr_w,
                                                const float* __restrict__ Xin,
                                                float* __restrict__ Yout, int n) {
    int j = blockIdx.x * 4 + (threadIdx.x >> 6);
    if (j >= n) return;
    int lane = threadIdx.x & 63;
    int lo = offsets[j], hi = offsets[j + 1];
    const float2* __restrict__ X2 = (const float2*)Xin;
    float2 acc = {0.f, 0.f};
    for (int e = lo; e < hi; ++e) {
        int s = csr_src[e];
        float w = csr_w[e];
        float2 x = X2[(size_t)s * 64 + lane];
        acc.x += w * x.x;
        acc.y += w * x.y;
    }
    ((float2*)Yout)[(size_t)j * 64 + lane] = acc;
}

// ---------------- final: normalize rows + H @ Vw^T ----------------

__global__ __launch_bounds__(128) void final_out(const float* __restrict__ Xt,
                                                 const float* __restrict__ Vw,
                                                 float* __restrict__ out) {
    __shared__ float h[128];
    __shared__ float red[2];
    int j = blockIdx.x, t = threadIdx.x;
    float x = Xt[(size_t)j * 128 + t];
    float s = x * x;
    for (int o = 32; o > 0; o >>= 1) s += __shfl_down(s, o, 64);
    if ((t & 63) == 0) red[t >> 6] = s;
    __syncthreads();
    float norm = sqrtf(red[0] + red[1]);
    float inv = 1.f / fmaxf(norm, 1e-12f);
    h[t] = x * inv;
    __syncthreads();
    if (t < C_OUT) {
        float acc = 0.f;
        for (int k = 0; k < 128; ++k) acc += h[k] * Vw[t * 128 + k];
        out[(size_t)j * C_OUT + t] = acc;
    }
}

// ---------------- launch ----------------

extern "C" void kernel_launch(void* const* d_in, const int* in_sizes, int n_in,
                              void* d_out, int out_size, void* d_ws, size_t ws_size,
                              hipStream_t stream) {
    const float* F    = (const float*)d_in[0];   // (256, 50000)
    const float* W    = (const float*)d_in[1];   // (128, 128)
    const float* Om   = (const float*)d_in[2];   // (128, 256)
    const float* Vw   = (const float*)d_in[3];   // (40, 128)
    const float* X0   = (const float*)d_in[4];   // (128, 50000)
    const float* ew   = (const float*)d_in[5];   // (E,)
    const int*   esrc = (const int*)d_in[6];
    const int*   edst = (const int*)d_in[7];
    float* out = (float*)d_out;
    (void)in_sizes; (void)n_in; (void)out_size; (void)ws_size;

    char* ws = (char*)d_ws;
    size_t off = 0;
    auto alloc = [&](size_t bytes) -> void* {
        void* p = ws + off;
        off = (off + bytes + 255) & ~(size_t)255;
        return p;
    };
    float* buf0    = (float*)alloc((size_t)N_NODES * 4);
    float* buf1    = (float*)alloc((size_t)N_NODES * 4);
    float* ss      = (float*)alloc(64 * 4);
    int*   deg     = (int*)  alloc((size_t)(N_NODES + 1) * 4);
    int*   offs    = (int*)  alloc((size_t)(N_NODES + 1) * 4);
    int*   cursor  = (int*)  alloc((size_t)N_NODES * 4);
    int*   csr_src = (int*)  alloc((size_t)N_EDGES * 4);
    float* csr_w   = (float*)alloc((size_t)N_EDGES * 4);
    float* Wp      = (float*)alloc(128 * 128 * 4);
    float* WpT     = (float*)alloc(128 * 128 * 4);
    float* OmT     = (float*)alloc(256 * 128 * 4);
    float* bt      = (float*)alloc((size_t)N_NODES * 128 * 4);
    float* Yt      = (float*)alloc((size_t)N_NODES * 128 * 4);
    float* Xt      = (float*)alloc((size_t)N_NODES * 128 * 4);

    hipMemsetAsync(deg, 0, (size_t)(N_NODES + 1) * 4, stream);

    // ---- power iteration for spectral radius (2 kernels / iter) ----
    float* bufs[2] = {buf0, buf1};
    fill_pow<<<(N_NODES + 255) / 256, 256, 0, stream>>>(
        buf0, buf1, ss, N_NODES, 1.f / sqrtf((float)N_NODES));
    for (int it = 0; it < PWR_ITERS; ++it) {
        scatter_pow<<<(N_EDGES + 255) / 256, 256, 0, stream>>>(
            esrc, edst, ew, bufs[it & 1], ss + it, bufs[(it + 1) & 1], N_EDGES);
        reduce_zero<<<128, 256, 0, stream>>>(bufs[(it + 1) & 1], bufs[it & 1],
                                             N_NODES, ss + it + 1);
    }
    // final matvec on normalized v -> rho^2 in ss[51]
    scatter_pow<<<(N_EDGES + 255) / 256, 256, 0, stream>>>(
        esrc, edst, ew, bufs[0], ss + PWR_ITERS, bufs[1], N_EDGES);
    reduce_zero<<<128, 256, 0, stream>>>(bufs[1], bufs[0], N_NODES, ss + PWR_ITERS + 1);

    // ---- project W rows onto L1 ball of radius kappa/rho ----
    project_w<<<128, 128, 0, stream>>>(W, ss + PWR_ITERS + 1, Wp, WpT);

    // ---- CSR by dst ----
    count_deg<<<(N_EDGES + 255) / 256, 256, 0, stream>>>(edst, deg, N_EDGES);
    scan_offsets<<<1, 1024, 0, stream>>>(deg, offs, cursor, N_NODES);
    fill_csr<<<(N_EDGES + 255) / 256, 256, 0, stream>>>(esrc, edst, ew, cursor,
                                                        csr_src, csr_w, N_EDGES);

    // ---- b = (Omega_1 @ U) @ A ----
    transpose_om<<<(128 * 256 + 255) / 256, 256, 0, stream>>>(Om, OmT);
    gemm_u<<<(N_NODES + 127) / 128, 256, 0, stream>>>(F, OmT, Yt, N_NODES);   // Ut in Yt
    spmm_csr<<<(N_NODES + 3) / 4, 256, 0, stream>>>(offs, csr_src, csr_w, Yt, bt, N_NODES);

    // ---- fixed point ----
    transpose_x0<<<dim3((N_NODES + 31) / 32, 4), dim3(32, 8), 0, stream>>>(X0, Xt, N_NODES);
    for (int it = 0; it < FP_ITERS; ++it) {
        spmm_csr<<<(N_NODES + 3) / 4, 256, 0, stream>>>(offs, csr_src, csr_w, Xt, Yt, N_NODES);
        gemm_relu<<<(N_NODES + 127) / 128, 256, 0, stream>>>(Yt, WpT, bt, Xt, N_NODES);
    }

    // ---- output ----
    final_out<<<N_NODES, 128, 0, stream>>>(Xt, Vw, out);
}